// Round 4
// baseline (293.035 us; speedup 1.0000x reference)
//
#include <hip/hip_runtime.h>

#define N_NODES 50000
#define N_EDGES 800000
#define D 128
#define PLANE ((size_t)N_NODES * D)
#define NBAND 16
#define BANDW 3125                      // 50000 / 16 srcs per band
#define NB2 (N_NODES * NBAND)           // 800000 (row,band) keys
#define NW2 (NB2 / 4)                   // 200000 packed counter words
#define NCHUNK2 (NB2 / 256)             // 3125 (exact)
#define NROWBLK ((N_NODES + 255) / 256) // 196

typedef float f32x4 __attribute__((ext_vector_type(4)));
typedef float f32x2 __attribute__((ext_vector_type(2)));
typedef short bf16x8 __attribute__((ext_vector_type(8)));

__device__ __forceinline__ unsigned short f2bf(float x) {
  unsigned int u = __float_as_uint(x);
  u += 0x7FFFu + ((u >> 16) & 1u);  // RNE
  return (unsigned short)(u >> 16);
}
// HW OCP e4m3 convert (gfx950)
__device__ __forceinline__ unsigned char f32_to_fp8(float x) {
  int p = __builtin_amdgcn_cvt_pk_fp8_f32(x, x, 0, false);
  return (unsigned char)(p & 0xFF);
}
__device__ __forceinline__ int band_of(int s) { return (int)((unsigned)s / (unsigned)BANDW); }
__device__ __forceinline__ int unpack_cnt(const unsigned* c2, int key) {
  return (int)((c2[key >> 2] >> ((key & 3) * 8)) & 0xFFu);
}
__device__ __forceinline__ int row_degree(const unsigned* c2, int row) {
  const unsigned* c = c2 + row * 4;  // 4 words = 16 byte counters
  int d = 0;
#pragma unroll
  for (int w = 0; w < 4; ++w) {
    unsigned x = c[w];
    d += (int)((x & 0xFF) + ((x >> 8) & 0xFF) + ((x >> 16) & 0xFF) + (x >> 24));
  }
  return d;
}

// ---------------- scans: per-(row,band) packed counts -> band-sorted rowptr2 -------

// blocks [0,NCHUNK2): 256-key local scan.  blocks [NCHUNK2, +NROWBLK): degree hist.
__global__ __launch_bounds__(256) void scan_local2(const unsigned* __restrict__ cnt2p,
                                                   int* __restrict__ local2,
                                                   int* __restrict__ partial,
                                                   int* __restrict__ bcnt) {
  __shared__ int s[256];
  __shared__ int hist[64];
  int t = threadIdx.x;
  if (blockIdx.x < NCHUNK2) {
    int i = blockIdx.x * 256 + t;  // key index, < NB2
    int v = unpack_cnt(cnt2p, i);
    s[t] = v;
    __syncthreads();
    for (int off = 1; off < 256; off <<= 1) {
      int tmp = (t >= off) ? s[t - off] : 0;
      __syncthreads();
      s[t] += tmp;
      __syncthreads();
    }
    local2[i] = s[t] - v;
    if (t == 255) partial[blockIdx.x] = s[255];
    return;
  }
  if (t < 64) hist[t] = 0;
  __syncthreads();
  int i = (blockIdx.x - NCHUNK2) * 256 + t;
  if (i < N_NODES) {
    int d = row_degree(cnt2p, i);
    atomicAdd(&hist[d < 63 ? d : 63], 1);
  }
  __syncthreads();
  if (t < 64 && hist[t]) atomicAdd(&bcnt[t], hist[t]);
}

// single block: scan the 3125 block-partials (13/thread) + degree-bucket bases.
__global__ __launch_bounds__(256) void scan_chunks2(const int* __restrict__ partial,
                                                    int* __restrict__ chunk_off,
                                                    int* __restrict__ rowptr2_last,
                                                    const int* __restrict__ bcnt,
                                                    int* __restrict__ gcur) {
  __shared__ int s[256];
  const int PER = (NCHUNK2 + 255) / 256;  // 13
  int t = threadIdx.x;
  int loc[PER];
  int run = 0;
#pragma unroll
  for (int j = 0; j < PER; ++j) {
    int idx = t * PER + j;
    int v = (idx < NCHUNK2) ? partial[idx] : 0;
    loc[j] = run;
    run += v;
  }
  s[t] = run;
  __syncthreads();
  for (int off = 1; off < 256; off <<= 1) {
    int tmp = (t >= off) ? s[t - off] : 0;
    __syncthreads();
    s[t] += tmp;
    __syncthreads();
  }
  int base = s[t] - run;
#pragma unroll
  for (int j = 0; j < PER; ++j) {
    int idx = t * PER + j;
    if (idx < NCHUNK2) chunk_off[idx] = base + loc[j];
  }
  if (t == 255) rowptr2_last[0] = s[255];  // == N_EDGES
  if (t == 0) {
    int r2 = 0;
    for (int q = 0; q < 64; ++q) {
      gcur[q] = r2;
      r2 += bcnt[q];
    }
  }
}

// blocks [0,NCHUNK2): finalize rowptr2.  blocks [NCHUNK2,+NROWBLK): norm + perm.
__global__ __launch_bounds__(256) void finalize2(const int* __restrict__ local2,
                                                 const int* __restrict__ chunk_off,
                                                 const unsigned* __restrict__ cnt2p,
                                                 int* __restrict__ rowptr2,
                                                 float* __restrict__ norm,
                                                 int* __restrict__ gcur,
                                                 int* __restrict__ perm) {
  __shared__ int hcnt[64];
  __shared__ int hbase[64];
  int t = threadIdx.x;
  if (blockIdx.x < NCHUNK2) {
    int i = blockIdx.x * 256 + t;
    rowptr2[i] = local2[i] + chunk_off[blockIdx.x];
    return;
  }
  if (t < 64) hcnt[t] = 0;
  __syncthreads();
  int i = (blockIdx.x - NCHUNK2) * 256 + t;
  int b = 0;
  if (i < N_NODES) {
    int d = row_degree(cnt2p, i);
    b = d < 63 ? d : 63;
    atomicAdd(&hcnt[b], 1);
    norm[i] = rsqrtf((float)(d < 1 ? 1 : d));
  }
  __syncthreads();
  if (t < 64) {
    hbase[t] = atomicAdd(&gcur[t], hcnt[t]);
    hcnt[t] = 0;
  }
  __syncthreads();
  if (i < N_NODES) {
    int lp = atomicAdd(&hcnt[b], 1);
    perm[hbase[b] + lp] = i;
  }
}

// ---------------- prep: EDGES-FIRST (hide atomic latency under streaming) ----------
// Grid order: [edges: count+rank atomics] -> [weight transposes] -> [feats->bf16].
// The edge waves launch first and stall on device-scope atomic round-trips; the
// streaming conv waves behind them keep the CUs busy, so the atomic latency is
// overlapped instead of exposed at the kernel tail.

#define CONV_THREADS ((int)(PLANE / 4))            // 1,600,000
#define WT_THREADS (2 * 3 * 128 * 256)             // 196,608
#define PREP_TOTAL (CONV_THREADS + WT_THREADS + N_EDGES)

__global__ __launch_bounds__(256) void prep_all(const float* __restrict__ feats,
                                                const float* __restrict__ w0,
                                                const float* __restrict__ w,
                                                const float* __restrict__ v,
                                                const int* __restrict__ src,
                                                const int* __restrict__ dst,
                                                unsigned short* __restrict__ feats_bf,
                                                unsigned short* __restrict__ bt_h1,
                                                unsigned short* __restrict__ bt_out,
                                                unsigned* __restrict__ cnt2p,
                                                int* __restrict__ rank_pack) {
  int idx = blockIdx.x * 256 + threadIdx.x;
  if (idx < N_EDGES) {
    int dd = dst[idx];
    int ss = src[idx];
    int key = dd * NBAND + band_of(ss);
    int sh = (key & 3) * 8;
    unsigned old = atomicAdd(&cnt2p[key >> 2], 1u << sh);  // count AND rank in one op
    int rank = (int)((old >> sh) & 0xFFu);
    rank_pack[idx] = (key << 8) | rank;  // coalesced; key<2^20, rank<256
    return;
  }
  idx -= N_EDGES;
  if (idx < WT_THREADS) {
    int buf = idx / 98304;
    int rem = idx - buf * 98304;
    int stack = rem / 32768;
    int rem2 = rem & 32767;
    int n = rem2 >> 8;
    int k = rem2 & 255;
    const float* srcm;
    int kk;
    if (k < 128) {
      srcm = (buf == 0) ? w0 : w;
      kk = k;
    } else {
      srcm = v;
      kk = k - 128;
    }
    float val = srcm[(size_t)stack * 16384 + (size_t)kk * 128 + n];
    unsigned short* dstb = (buf == 0) ? bt_h1 : bt_out;
    dstb[(size_t)stack * 32768 + (size_t)n * 256 + k] = f2bf(val);
    return;
  }
  idx -= WT_THREADS;
  if (idx < CONV_THREADS) {
    float4 x = ((const float4*)feats)[idx];
    ushort4 o;
    o.x = f2bf(x.x);
    o.y = f2bf(x.y);
    o.z = f2bf(x.z);
    o.w = f2bf(x.w);
    ((ushort4*)feats_bf)[idx] = o;
  }
}

// atomic-free CSR fill (edges first) + feats_fp8 = fp8(norm * feats)
__global__ __launch_bounds__(256) void csr_fp8(const int* __restrict__ src,
                                               const int* __restrict__ rank_pack,
                                               const int* __restrict__ rowptr2,
                                               int* __restrict__ col,
                                               const float* __restrict__ feats,
                                               const float* __restrict__ norm,
                                               unsigned char* __restrict__ feats_fp8) {
  int idx = blockIdx.x * 256 + threadIdx.x;
  if (idx < N_EDGES) {
    int pk = rank_pack[idx];
    int key = (int)((unsigned)pk >> 8);
    int pos = rowptr2[key] + (pk & 255);
    col[pos] = src[idx];  // scatter store, no atomic dependency chain
    return;
  }
  idx -= N_EDGES;
  if (idx < CONV_THREADS) {
    float4 x = ((const float4*)feats)[idx];
    float nv = norm[idx >> 5];  // 32 float4 per 128-feat row
    int p = __builtin_amdgcn_cvt_pk_fp8_f32(x.x * nv, x.y * nv, 0, false);
    p = __builtin_amdgcn_cvt_pk_fp8_f32(x.z * nv, x.w * nv, p, true);
    ((int*)feats_fp8)[idx] = p;
  }
}

// ---------------- SpMM: 8 lanes/row, band-sorted cols, 4-edge unroll, heavy-first --

template <int NK, int STRIDE>
__global__ __launch_bounds__(256) void spmm_rows(const unsigned char* __restrict__ h,
                                                 const float* __restrict__ norm,
                                                 const int* __restrict__ rowptr2,
                                                 const int* __restrict__ col,
                                                 const int* __restrict__ perm,
                                                 unsigned short* __restrict__ out) {
  int gi = blockIdx.x * 32 + (threadIdx.x >> 3);
  if (gi >= N_NODES) return;
  int l = threadIdx.x & 7;
  int row = perm[N_NODES - 1 - gi];  // heavy rows first -> thin tail
  int beg = rowptr2[row * NBAND];
  int end = rowptr2[row * NBAND + NBAND];

  f32x2 acc[NK][8];
#pragma unroll
  for (int m = 0; m < NK; ++m)
#pragma unroll
    for (int j = 0; j < 8; ++j) acc[m][j] = (f32x2)(0.f);

  auto accum = [&](int m, int4 p) {
    acc[m][0] += __builtin_amdgcn_cvt_pk_f32_fp8(p.x, false);
    acc[m][1] += __builtin_amdgcn_cvt_pk_f32_fp8(p.x, true);
    acc[m][2] += __builtin_amdgcn_cvt_pk_f32_fp8(p.y, false);
    acc[m][3] += __builtin_amdgcn_cvt_pk_f32_fp8(p.y, true);
    acc[m][4] += __builtin_amdgcn_cvt_pk_f32_fp8(p.z, false);
    acc[m][5] += __builtin_amdgcn_cvt_pk_f32_fp8(p.z, true);
    acc[m][6] += __builtin_amdgcn_cvt_pk_f32_fp8(p.w, false);
    acc[m][7] += __builtin_amdgcn_cvt_pk_f32_fp8(p.w, true);
  };
  auto edge1 = [&](int s) {
    const unsigned char* hp = h + (size_t)s * STRIDE + l * 16;
#pragma unroll
    for (int m = 0; m < NK; ++m) accum(m, *(const int4*)(hp + m * 128));
  };

  int e = beg;
  int pe = beg + ((4 - (beg & 3)) & 3);  // peel to 16B-aligned col index
  if (pe > end) pe = end;
  for (; e < pe; ++e) edge1(col[e]);
  for (; e + 4 <= end; e += 4) {
    int4 cc = *(const int4*)(col + e);  // one aligned load for 4 edge ids
    const unsigned char* p0 = h + (size_t)cc.x * STRIDE + l * 16;
    const unsigned char* p1 = h + (size_t)cc.y * STRIDE + l * 16;
    const unsigned char* p2 = h + (size_t)cc.z * STRIDE + l * 16;
    const unsigned char* p3 = h + (size_t)cc.w * STRIDE + l * 16;
#pragma unroll
    for (int m = 0; m < NK; ++m) {
      int4 q0 = *(const int4*)(p0 + m * 128);
      int4 q1 = *(const int4*)(p1 + m * 128);
      int4 q2 = *(const int4*)(p2 + m * 128);
      int4 q3 = *(const int4*)(p3 + m * 128);
      accum(m, q0);
      accum(m, q1);
      accum(m, q2);
      accum(m, q3);
    }
  }
  for (; e < end; ++e) edge1(col[e]);

  float nd = norm[row];
#pragma unroll
  for (int m = 0; m < NK; ++m) {
    bf16x8 o0, o1;
#pragma unroll
    for (int j = 0; j < 4; ++j) {
      o0[2 * j] = (short)f2bf(acc[m][j].x * nd);
      o0[2 * j + 1] = (short)f2bf(acc[m][j].y * nd);
      o1[2 * j] = (short)f2bf(acc[m][j + 4].x * nd);
      o1[2 * j + 1] = (short)f2bf(acc[m][j + 4].y * nd);
    }
    unsigned short* op = out + (size_t)m * PLANE + (size_t)row * D + l * 16;
    *(bf16x8*)op = o0;
    *(bf16x8*)(op + 8) = o1;
  }
}

// ---------------- MFMA GEMM ----------------
// Block: 256 threads = 4 waves, M-tile 128 rows, N-tile 64 cols (blockIdx.y).
// B half-tile (64n x 256k bf16 = 32 KB) in LDS, XOR-swizzled (2-way max).

__device__ __forceinline__ void stage_B64(unsigned short (*Bs)[256],
                                          const unsigned short* __restrict__ Btg,
                                          int nh, int tid) {
#pragma unroll
  for (int i = 0; i < 8; ++i) {
    int t = tid + i * 256;       // 0..2047 16B-chunks
    int n = t >> 5;              // 0..63
    int kc = t & 31;
    int kcs = kc ^ (n & 31);     // swizzle
    *(bf16x8*)&Bs[n][kcs * 8] = *(const bf16x8*)(Btg + (size_t)(nh + n) * 256 + kc * 8);
  }
}

__device__ __forceinline__ bf16x8 read_B64(const unsigned short (*Bs)[256], int n,
                                           int chunk) {
  return *(const bf16x8*)&Bs[n][(chunk ^ (n & 31)) * 8];
}

// layer-1: h1[node][stk][128] = fp8( norm[node] * relu(P @ w0[stk] + feats @ v[stk] + b) )
__global__ __launch_bounds__(256) void gemm_h1_fused(
    const unsigned short* __restrict__ P,
    const unsigned short* __restrict__ feats_bf,
    const unsigned short* __restrict__ Bt,
    const float* __restrict__ b0, const float* __restrict__ bv,
    const float* __restrict__ norm,
    unsigned char* __restrict__ h1_fp8) {
  __shared__ unsigned short Bs[64][256];
  int nh = blockIdx.y * 64;

  int tid = threadIdx.x;
  int lane = tid & 63;
  int wv = tid >> 6;
  int ln15 = lane & 15;
  int g = lane >> 4;

  int m0 = blockIdx.x * 128 + wv * 32;
  int r0 = m0 + ln15;
  int r1 = m0 + 16 + ln15;
  if (r0 >= N_NODES) r0 = N_NODES - 1;
  if (r1 >= N_NODES) r1 = N_NODES - 1;

  bf16x8 a0[8], a1[8];  // s=0..3 from P (k<128), s=4..7 from feats (k>=128)
#pragma unroll
  for (int s = 0; s < 4; ++s) {
    a0[s] = *(const bf16x8*)(P + (size_t)r0 * 128 + g * 8 + s * 32);
    a1[s] = *(const bf16x8*)(P + (size_t)r1 * 128 + g * 8 + s * 32);
    a0[s + 4] = *(const bf16x8*)(feats_bf + (size_t)r0 * 128 + g * 8 + s * 32);
    a1[s + 4] = *(const bf16x8*)(feats_bf + (size_t)r1 * 128 + g * 8 + s * 32);
  }

  float nA[4], nB[4];
#pragma unroll
  for (int r = 0; r < 4; ++r) {
    int mA = m0 + g * 4 + r;
    int mB = m0 + 16 + g * 4 + r;
    nA[r] = (mA < N_NODES) ? norm[mA] : 0.f;
    nB[r] = (mB < N_NODES) ? norm[mB] : 0.f;
  }

  for (int stk = 0; stk < 3; ++stk) {
    if (stk) __syncthreads();
    stage_B64(Bs, Bt + (size_t)stk * 32768, nh, tid);
    __syncthreads();

    f32x4 acc0[4], acc1[4];
#pragma unroll
    for (int nt = 0; nt < 4; ++nt) { acc0[nt] = (f32x4)(0.f); acc1[nt] = (f32x4)(0.f); }

#pragma unroll
    for (int s = 0; s < 8; ++s) {
#pragma unroll
      for (int nt = 0; nt < 4; ++nt) {
        bf16x8 bfr = read_B64(Bs, nt * 16 + ln15, s * 4 + g);
        acc0[nt] = __builtin_amdgcn_mfma_f32_16x16x32_bf16(a0[s], bfr, acc0[nt], 0, 0, 0);
        acc1[nt] = __builtin_amdgcn_mfma_f32_16x16x32_bf16(a1[s], bfr, acc1[nt], 0, 0, 0);
      }
    }

#pragma unroll
    for (int nt = 0; nt < 4; ++nt) {
      int colj = nh + nt * 16 + ln15;
      float bsum = b0[stk * 128 + colj] + bv[stk * 128 + colj];
#pragma unroll
      for (int r = 0; r < 4; ++r) {
        int mA = m0 + g * 4 + r;
        int mB = m0 + 16 + g * 4 + r;
        if (mA < N_NODES) {
          float x = acc0[nt][r] + bsum;
          x = x > 0.f ? x : 0.f;
          h1_fp8[(size_t)mA * 384 + stk * 128 + colj] = f32_to_fp8(x * nA[r]);
        }
        if (mB < N_NODES) {
          float x = acc1[nt][r] + bsum;
          x = x > 0.f ? x : 0.f;
          h1_fp8[(size_t)mB * 384 + stk * 128 + colj] = f32_to_fp8(x * nB[r]);
        }
      }
    }
  }
}

// layer-2 fused: out = (1/3) * sum_stk relu(agg[stk] @ w[stk] + feats @ v[stk] + bw + bv)
__global__ __launch_bounds__(256) void gemm_out_fused(
    const unsigned short* __restrict__ agg,
    const unsigned short* __restrict__ feats_bf,
    const unsigned short* __restrict__ Bt,
    const float* __restrict__ bwp, const float* __restrict__ bvp,
    float* __restrict__ outp) {
  __shared__ unsigned short Bs[64][256];
  int nh = blockIdx.y * 64;

  int tid = threadIdx.x;
  int lane = tid & 63;
  int wv = tid >> 6;
  int ln15 = lane & 15;
  int g = lane >> 4;

  int m0 = blockIdx.x * 128 + wv * 32;
  int r0 = m0 + ln15;
  int r1 = m0 + 16 + ln15;
  if (r0 >= N_NODES) r0 = N_NODES - 1;
  if (r1 >= N_NODES) r1 = N_NODES - 1;

  bf16x8 f0[4], f1[4];  // feats frags (k=128..255 phase)
#pragma unroll
  for (int s = 0; s < 4; ++s) {
    f0[s] = *(const bf16x8*)(feats_bf + (size_t)r0 * 128 + g * 8 + s * 32);
    f1[s] = *(const bf16x8*)(feats_bf + (size_t)r1 * 128 + g * 8 + s * 32);
  }

  f32x4 sum0[4], sum1[4];
#pragma unroll
  for (int nt = 0; nt < 4; ++nt) { sum0[nt] = (f32x4)(0.f); sum1[nt] = (f32x4)(0.f); }

  for (int stk = 0; stk < 3; ++stk) {
    if (stk) __syncthreads();
    stage_B64(Bs, Bt + (size_t)stk * 32768, nh, tid);
    __syncthreads();

    const unsigned short* A1 = agg + (size_t)stk * PLANE;
    bf16x8 g0[4], g1[4];
#pragma unroll
    for (int s = 0; s < 4; ++s) {
      g0[s] = *(const bf16x8*)(A1 + (size_t)r0 * 128 + g * 8 + s * 32);
      g1[s] = *(const bf16x8*)(A1 + (size_t)r1 * 128 + g * 8 + s * 32);
    }

    f32x4 acc0[4], acc1[4];
#pragma unroll
    for (int nt = 0; nt < 4; ++nt) { acc0[nt] = (f32x4)(0.f); acc1[nt] = (f32x4)(0.f); }

#pragma unroll
    for (int s = 0; s < 8; ++s) {
      bf16x8 af0 = (s < 4) ? g0[s & 3] : f0[s & 3];
      bf16x8 af1 = (s < 4) ? g1[s & 3] : f1[s & 3];
#pragma unroll
      for (int nt = 0; nt < 4; ++nt) {
        bf16x8 bfr = read_B64(Bs, nt * 16 + ln15, s * 4 + g);
        acc0[nt] = __builtin_amdgcn_mfma_f32_16x16x32_bf16(af0, bfr, acc0[nt], 0, 0, 0);
        acc1[nt] = __builtin_amdgcn_mfma_f32_16x16x32_bf16(af1, bfr, acc1[nt], 0, 0, 0);
      }
    }

#pragma unroll
    for (int nt = 0; nt < 4; ++nt) {
      int colj = nh + nt * 16 + ln15;
      float bsum = bwp[stk * 128 + colj] + bvp[stk * 128 + colj];
#pragma unroll
      for (int r = 0; r < 4; ++r) {
        float x0 = acc0[nt][r] + bsum;
        float x1 = acc1[nt][r] + bsum;
        sum0[nt][r] += (x0 > 0.f ? x0 : 0.f);
        sum1[nt][r] += (x1 > 0.f ? x1 : 0.f);
      }
    }
  }

  const float sc = 1.0f / 3.0f;
#pragma unroll
  for (int nt = 0; nt < 4; ++nt) {
    int colj = nh + nt * 16 + ln15;
#pragma unroll
    for (int r = 0; r < 4; ++r) {
      int mA = m0 + g * 4 + r;
      int mB = m0 + 16 + g * 4 + r;
      if (mA < N_NODES) outp[(size_t)mA * 128 + colj] = sum0[nt][r] * sc;
      if (mB < N_NODES) outp[(size_t)mB * 128 + colj] = sum1[nt][r] * sc;
    }
  }
}

// ---------------- launcher ----------------

extern "C" void kernel_launch(void* const* d_in, const int* in_sizes, int n_in,
                              void* d_out, int out_size, void* d_ws, size_t ws_size,
                              hipStream_t stream) {
  const float* feats = (const float*)d_in[0];
  const int* src = (const int*)d_in[1];
  const int* dst = (const int*)d_in[2];
  const float* w0 = (const float*)d_in[3];
  const float* b0 = (const float*)d_in[4];
  const float* w = (const float*)d_in[5];
  const float* bw = (const float*)d_in[6];
  const float* v = (const float*)d_in[7];
  const float* bv = (const float*)d_in[8];
  float* out = (float*)d_out;

  char* ws = (char*)d_ws;
  size_t off = 0;
  auto alloc = [&](size_t bytes) {
    void* p = ws + off;
    off += (bytes + 255) & ~(size_t)255;
    return p;
  };
  // packed counters + bucket counters contiguous so one memset clears all
  unsigned* cnt2p = (unsigned*)alloc((NW2 + 128) * 4);
  int* bcnt = (int*)cnt2p + NW2;
  int* gcur = bcnt + 64;
  int* local2 = (int*)alloc(NB2 * 4);
  int* partial = (int*)alloc(NCHUNK2 * 4);
  int* chunk_off = (int*)alloc(NCHUNK2 * 4);
  float* norm = (float*)alloc(N_NODES * 4);
  int* rowptr2 = (int*)alloc((NB2 + 1) * 4);
  int* col = (int*)alloc(N_EDGES * 4);
  int* perm = (int*)alloc(N_NODES * 4);
  int* rank_pack = (int*)alloc(N_EDGES * 4);
  unsigned short* bt_h1 = (unsigned short*)alloc(3 * 32768 * 2);
  unsigned short* bt_out = (unsigned short*)alloc(3 * 32768 * 2);

  size_t pb = PLANE * 2;  // bf16 plane bytes
  unsigned short* feats_bf = (unsigned short*)alloc(pb);
  unsigned char* feats_fp8 = (unsigned char*)alloc(PLANE);
  unsigned short* P_bf = (unsigned short*)alloc(pb);
  unsigned char* h1_fp8 = (unsigned char*)alloc(3 * PLANE);  // interleaved [node][3][128]
  unsigned short* agg_bf = (unsigned short*)alloc(3 * pb);

  hipMemsetAsync(cnt2p, 0, (NW2 + 128) * 4, stream);

  dim3 blk(256);
  // prep: edges-first (atomic latency overlapped by conv streaming behind it)
  prep_all<<<(PREP_TOTAL + 255) / 256, blk, 0, stream>>>(feats, w0, w, v, src, dst,
                                                         feats_bf, bt_h1, bt_out, cnt2p,
                                                         rank_pack);
  scan_local2<<<NCHUNK2 + NROWBLK, blk, 0, stream>>>(cnt2p, local2, partial, bcnt);
  scan_chunks2<<<1, blk, 0, stream>>>(partial, chunk_off, rowptr2 + NB2, bcnt, gcur);
  finalize2<<<NCHUNK2 + NROWBLK, blk, 0, stream>>>(local2, chunk_off, cnt2p, rowptr2,
                                                   norm, gcur, perm);
  // atomic-free band-sorted CSR fill (edges first) + feats_fp8 = fp8(norm * feats)
  csr_fp8<<<(CONV_THREADS + N_EDGES + 255) / 256, blk, 0, stream>>>(
      src, rank_pack, rowptr2, col, feats, norm, feats_fp8);

  int sblocks = (N_NODES + 31) / 32;  // 32 rows per block (8 lanes/row)
  int mblocks = (N_NODES + 127) / 128;
  dim3 ggrid(mblocks, 2);  // x: M-tile, y: N-half (stacks looped in-kernel)

  // P = propagate(feats)   (src-norm pre-folded; dst-norm in epilogue)
  spmm_rows<1, 128><<<sblocks, blk, 0, stream>>>(feats_fp8, norm, rowptr2, col, perm, P_bf);
  // h1[node][k][:] = fp8(norm * relu(P @ w0[k] + feats @ v[k] + b0[k] + bv[k]))
  gemm_h1_fused<<<ggrid, blk, 0, stream>>>(P_bf, feats_bf, bt_h1, b0, bv, norm, h1_fp8);
  // agg[k] = propagate(h1[k])  (interleaved gather: 384 B/edge contiguous, band-sorted)
  spmm_rows<3, 384><<<sblocks, blk, 0, stream>>>(h1_fp8, norm, rowptr2, col, perm, agg_bf);
  // out = (1/3) * sum_k relu(agg[k] @ w[k] + feats @ v[k] + bw[k] + bv[k])
  gemm_out_fused<<<ggrid, blk, 0, stream>>>(agg_bf, feats_bf, bt_out, bw, bv, out);
}

// Round 5
// 287.858 us; speedup vs baseline: 1.0180x; 1.0180x over previous
//
#include <hip/hip_runtime.h>

#define N_NODES 50000
#define N_EDGES 800000
#define D 128
#define PLANE ((size_t)N_NODES * D)
#define NBAND 16
#define BANDW 3125                      // 50000 / 16 srcs per band
#define NB2 (N_NODES * NBAND)           // 800000 (row,band) keys
#define NW2 (NB2 / 4)                   // 200000 packed counter words
#define NCHUNK2 (NB2 / 256)             // 3125 (exact)
#define NROWBLK ((N_NODES + 255) / 256) // 196
#define MBLOCKS ((N_NODES + 127) / 128) // 391
#define MGROUPS ((MBLOCKS + 7) / 8)     // 49
#define GEMM_GRID (MGROUPS * 16)        // 784 (8 M-tiles x 2 N-halves per group)

typedef float f32x4 __attribute__((ext_vector_type(4)));
typedef float f32x2 __attribute__((ext_vector_type(2)));
typedef short bf16x8 __attribute__((ext_vector_type(8)));

__device__ __forceinline__ unsigned short f2bf(float x) {
  unsigned int u = __float_as_uint(x);
  u += 0x7FFFu + ((u >> 16) & 1u);  // RNE
  return (unsigned short)(u >> 16);
}
// HW OCP e4m3 convert (gfx950)
__device__ __forceinline__ unsigned char f32_to_fp8(float x) {
  int p = __builtin_amdgcn_cvt_pk_fp8_f32(x, x, 0, false);
  return (unsigned char)(p & 0xFF);
}
__device__ __forceinline__ int band_of(int s) { return (int)((unsigned)s / (unsigned)BANDW); }
__device__ __forceinline__ int unpack_cnt(const unsigned* c2, int key) {
  return (int)((c2[key >> 2] >> ((key & 3) * 8)) & 0xFFu);
}
__device__ __forceinline__ int row_degree(const unsigned* c2, int row) {
  const unsigned* c = c2 + row * 4;  // 4 words = 16 byte counters
  int d = 0;
#pragma unroll
  for (int w = 0; w < 4; ++w) {
    unsigned x = c[w];
    d += (int)((x & 0xFF) + ((x >> 8) & 0xFF) + ((x >> 16) & 0xFF) + (x >> 24));
  }
  return d;
}

// XCD pair swizzle: dispatch slots d and d+8 map to the SAME M-tile with the two
// N-halves. blockIdx round-robins XCDs mod 8, so the pair lands on one XCD and the
// second member's A-operand loads hit that XCD's L2 (halves effective A traffic).
__device__ __forceinline__ void gemm_tile(int id, int* mb, int* nh) {
  int grp = id >> 4;
  int wj = id & 15;
  *mb = grp * 8 + (wj & 7);
  *nh = (wj >> 3) * 64;
}

// ---------------- scans: per-(row,band) packed counts -> band-sorted rowptr2 -------

// blocks [0,NCHUNK2): 256-key local scan.  blocks [NCHUNK2, +NROWBLK): degree hist.
__global__ __launch_bounds__(256) void scan_local2(const unsigned* __restrict__ cnt2p,
                                                   int* __restrict__ local2,
                                                   int* __restrict__ partial,
                                                   int* __restrict__ bcnt) {
  __shared__ int s[256];
  __shared__ int hist[64];
  int t = threadIdx.x;
  if (blockIdx.x < NCHUNK2) {
    int i = blockIdx.x * 256 + t;  // key index, < NB2
    int v = unpack_cnt(cnt2p, i);
    s[t] = v;
    __syncthreads();
    for (int off = 1; off < 256; off <<= 1) {
      int tmp = (t >= off) ? s[t - off] : 0;
      __syncthreads();
      s[t] += tmp;
      __syncthreads();
    }
    local2[i] = s[t] - v;
    if (t == 255) partial[blockIdx.x] = s[255];
    return;
  }
  if (t < 64) hist[t] = 0;
  __syncthreads();
  int i = (blockIdx.x - NCHUNK2) * 256 + t;
  if (i < N_NODES) {
    int d = row_degree(cnt2p, i);
    atomicAdd(&hist[d < 63 ? d : 63], 1);
  }
  __syncthreads();
  if (t < 64 && hist[t]) atomicAdd(&bcnt[t], hist[t]);
}

// single block: scan the 3125 block-partials (13/thread) + degree-bucket bases.
__global__ __launch_bounds__(256) void scan_chunks2(const int* __restrict__ partial,
                                                    int* __restrict__ chunk_off,
                                                    int* __restrict__ rowptr2_last,
                                                    const int* __restrict__ bcnt,
                                                    int* __restrict__ gcur) {
  __shared__ int s[256];
  const int PER = (NCHUNK2 + 255) / 256;  // 13
  int t = threadIdx.x;
  int loc[PER];
  int run = 0;
#pragma unroll
  for (int j = 0; j < PER; ++j) {
    int idx = t * PER + j;
    int v = (idx < NCHUNK2) ? partial[idx] : 0;
    loc[j] = run;
    run += v;
  }
  s[t] = run;
  __syncthreads();
  for (int off = 1; off < 256; off <<= 1) {
    int tmp = (t >= off) ? s[t - off] : 0;
    __syncthreads();
    s[t] += tmp;
    __syncthreads();
  }
  int base = s[t] - run;
#pragma unroll
  for (int j = 0; j < PER; ++j) {
    int idx = t * PER + j;
    if (idx < NCHUNK2) chunk_off[idx] = base + loc[j];
  }
  if (t == 255) rowptr2_last[0] = s[255];  // == N_EDGES
  if (t == 0) {
    int r2 = 0;
    for (int q = 0; q < 64; ++q) {
      gcur[q] = r2;
      r2 += bcnt[q];
    }
  }
}

// blocks [0,NCHUNK2): finalize rowptr2.  blocks [NCHUNK2,+NROWBLK): norm + perm.
__global__ __launch_bounds__(256) void finalize2(const int* __restrict__ local2,
                                                 const int* __restrict__ chunk_off,
                                                 const unsigned* __restrict__ cnt2p,
                                                 int* __restrict__ rowptr2,
                                                 float* __restrict__ norm,
                                                 int* __restrict__ gcur,
                                                 int* __restrict__ perm) {
  __shared__ int hcnt[64];
  __shared__ int hbase[64];
  int t = threadIdx.x;
  if (blockIdx.x < NCHUNK2) {
    int i = blockIdx.x * 256 + t;
    rowptr2[i] = local2[i] + chunk_off[blockIdx.x];
    return;
  }
  if (t < 64) hcnt[t] = 0;
  __syncthreads();
  int i = (blockIdx.x - NCHUNK2) * 256 + t;
  int b = 0;
  if (i < N_NODES) {
    int d = row_degree(cnt2p, i);
    b = d < 63 ? d : 63;
    atomicAdd(&hcnt[b], 1);
    norm[i] = rsqrtf((float)(d < 1 ? 1 : d));
  }
  __syncthreads();
  if (t < 64) {
    hbase[t] = atomicAdd(&gcur[t], hcnt[t]);
    hcnt[t] = 0;
  }
  __syncthreads();
  if (i < N_NODES) {
    int lp = atomicAdd(&hcnt[b], 1);
    perm[hbase[b] + lp] = i;
  }
}

// ---------------- prep: EDGES-FIRST (hide atomic latency under streaming) ----------

#define CONV_THREADS ((int)(PLANE / 4))            // 1,600,000
#define WT_THREADS (2 * 3 * 128 * 256)             // 196,608
#define PREP_TOTAL (CONV_THREADS + WT_THREADS + N_EDGES)

__global__ __launch_bounds__(256) void prep_all(const float* __restrict__ feats,
                                                const float* __restrict__ w0,
                                                const float* __restrict__ w,
                                                const float* __restrict__ v,
                                                const int* __restrict__ src,
                                                const int* __restrict__ dst,
                                                unsigned short* __restrict__ feats_bf,
                                                unsigned short* __restrict__ bt_h1,
                                                unsigned short* __restrict__ bt_out,
                                                unsigned* __restrict__ cnt2p,
                                                int* __restrict__ rank_pack) {
  int idx = blockIdx.x * 256 + threadIdx.x;
  if (idx < N_EDGES) {
    int dd = dst[idx];
    int ss = src[idx];
    int key = dd * NBAND + band_of(ss);
    int sh = (key & 3) * 8;
    unsigned old = atomicAdd(&cnt2p[key >> 2], 1u << sh);  // count AND rank in one op
    int rank = (int)((old >> sh) & 0xFFu);
    rank_pack[idx] = (key << 8) | rank;  // coalesced; key<2^20, rank<256
    return;
  }
  idx -= N_EDGES;
  if (idx < WT_THREADS) {
    int buf = idx / 98304;
    int rem = idx - buf * 98304;
    int stack = rem / 32768;
    int rem2 = rem & 32767;
    int n = rem2 >> 8;
    int k = rem2 & 255;
    const float* srcm;
    int kk;
    if (k < 128) {
      srcm = (buf == 0) ? w0 : w;
      kk = k;
    } else {
      srcm = v;
      kk = k - 128;
    }
    float val = srcm[(size_t)stack * 16384 + (size_t)kk * 128 + n];
    unsigned short* dstb = (buf == 0) ? bt_h1 : bt_out;
    dstb[(size_t)stack * 32768 + (size_t)n * 256 + k] = f2bf(val);
    return;
  }
  idx -= WT_THREADS;
  if (idx < CONV_THREADS) {
    float4 x = ((const float4*)feats)[idx];
    ushort4 o;
    o.x = f2bf(x.x);
    o.y = f2bf(x.y);
    o.z = f2bf(x.z);
    o.w = f2bf(x.w);
    ((ushort4*)feats_bf)[idx] = o;
  }
}

// atomic-free CSR fill (edges first) + feats_fp8 = fp8(norm * feats)
__global__ __launch_bounds__(256) void csr_fp8(const int* __restrict__ src,
                                               const int* __restrict__ rank_pack,
                                               const int* __restrict__ rowptr2,
                                               int* __restrict__ col,
                                               const float* __restrict__ feats,
                                               const float* __restrict__ norm,
                                               unsigned char* __restrict__ feats_fp8) {
  int idx = blockIdx.x * 256 + threadIdx.x;
  if (idx < N_EDGES) {
    int pk = rank_pack[idx];
    int key = (int)((unsigned)pk >> 8);
    int pos = rowptr2[key] + (pk & 255);
    col[pos] = src[idx];  // scatter store, no atomic dependency chain
    return;
  }
  idx -= N_EDGES;
  if (idx < CONV_THREADS) {
    float4 x = ((const float4*)feats)[idx];
    float nv = norm[idx >> 5];  // 32 float4 per 128-feat row
    int p = __builtin_amdgcn_cvt_pk_fp8_f32(x.x * nv, x.y * nv, 0, false);
    p = __builtin_amdgcn_cvt_pk_fp8_f32(x.z * nv, x.w * nv, p, true);
    ((int*)feats_fp8)[idx] = p;
  }
}

// ---------------- SpMM: 8 lanes/row, band-sorted cols, 4-edge unroll, heavy-first --

template <int NK, int STRIDE>
__global__ __launch_bounds__(256) void spmm_rows(const unsigned char* __restrict__ h,
                                                 const float* __restrict__ norm,
                                                 const int* __restrict__ rowptr2,
                                                 const int* __restrict__ col,
                                                 const int* __restrict__ perm,
                                                 unsigned short* __restrict__ out) {
  int gi = blockIdx.x * 32 + (threadIdx.x >> 3);
  if (gi >= N_NODES) return;
  int l = threadIdx.x & 7;
  int row = perm[N_NODES - 1 - gi];  // heavy rows first -> thin tail
  int beg = rowptr2[row * NBAND];
  int end = rowptr2[row * NBAND + NBAND];

  f32x2 acc[NK][8];
#pragma unroll
  for (int m = 0; m < NK; ++m)
#pragma unroll
    for (int j = 0; j < 8; ++j) acc[m][j] = (f32x2)(0.f);

  auto accum = [&](int m, int4 p) {
    acc[m][0] += __builtin_amdgcn_cvt_pk_f32_fp8(p.x, false);
    acc[m][1] += __builtin_amdgcn_cvt_pk_f32_fp8(p.x, true);
    acc[m][2] += __builtin_amdgcn_cvt_pk_f32_fp8(p.y, false);
    acc[m][3] += __builtin_amdgcn_cvt_pk_f32_fp8(p.y, true);
    acc[m][4] += __builtin_amdgcn_cvt_pk_f32_fp8(p.z, false);
    acc[m][5] += __builtin_amdgcn_cvt_pk_f32_fp8(p.z, true);
    acc[m][6] += __builtin_amdgcn_cvt_pk_f32_fp8(p.w, false);
    acc[m][7] += __builtin_amdgcn_cvt_pk_f32_fp8(p.w, true);
  };
  auto edge1 = [&](int s) {
    const unsigned char* hp = h + (size_t)s * STRIDE + l * 16;
#pragma unroll
    for (int m = 0; m < NK; ++m) accum(m, *(const int4*)(hp + m * 128));
  };

  int e = beg;
  int pe = beg + ((4 - (beg & 3)) & 3);  // peel to 16B-aligned col index
  if (pe > end) pe = end;
  for (; e < pe; ++e) edge1(col[e]);
  for (; e + 4 <= end; e += 4) {
    int4 cc = *(const int4*)(col + e);  // one aligned load for 4 edge ids
    const unsigned char* p0 = h + (size_t)cc.x * STRIDE + l * 16;
    const unsigned char* p1 = h + (size_t)cc.y * STRIDE + l * 16;
    const unsigned char* p2 = h + (size_t)cc.z * STRIDE + l * 16;
    const unsigned char* p3 = h + (size_t)cc.w * STRIDE + l * 16;
#pragma unroll
    for (int m = 0; m < NK; ++m) {
      int4 q0 = *(const int4*)(p0 + m * 128);
      int4 q1 = *(const int4*)(p1 + m * 128);
      int4 q2 = *(const int4*)(p2 + m * 128);
      int4 q3 = *(const int4*)(p3 + m * 128);
      accum(m, q0);
      accum(m, q1);
      accum(m, q2);
      accum(m, q3);
    }
  }
  for (; e < end; ++e) edge1(col[e]);

  float nd = norm[row];
#pragma unroll
  for (int m = 0; m < NK; ++m) {
    bf16x8 o0, o1;
#pragma unroll
    for (int j = 0; j < 4; ++j) {
      o0[2 * j] = (short)f2bf(acc[m][j].x * nd);
      o0[2 * j + 1] = (short)f2bf(acc[m][j].y * nd);
      o1[2 * j] = (short)f2bf(acc[m][j + 4].x * nd);
      o1[2 * j + 1] = (short)f2bf(acc[m][j + 4].y * nd);
    }
    unsigned short* op = out + (size_t)m * PLANE + (size_t)row * D + l * 16;
    *(bf16x8*)op = o0;
    *(bf16x8*)(op + 8) = o1;
  }
}

// ---------------- MFMA GEMM ----------------
// Block: 256 threads = 4 waves, M-tile 128 rows, N-half 64 cols (pair-swizzled 1D grid).
// B half-tile (64n x 256k bf16 = 32 KB) in LDS, XOR-swizzled (2-way max).

__device__ __forceinline__ void stage_B64(unsigned short (*Bs)[256],
                                          const unsigned short* __restrict__ Btg,
                                          int nh, int tid) {
#pragma unroll
  for (int i = 0; i < 8; ++i) {
    int t = tid + i * 256;       // 0..2047 16B-chunks
    int n = t >> 5;              // 0..63
    int kc = t & 31;
    int kcs = kc ^ (n & 31);     // swizzle
    *(bf16x8*)&Bs[n][kcs * 8] = *(const bf16x8*)(Btg + (size_t)(nh + n) * 256 + kc * 8);
  }
}

__device__ __forceinline__ bf16x8 read_B64(const unsigned short (*Bs)[256], int n,
                                           int chunk) {
  return *(const bf16x8*)&Bs[n][(chunk ^ (n & 31)) * 8];
}

// layer-1: h1[node][stk][128] = fp8( norm[node] * relu(P @ w0[stk] + feats @ v[stk] + b) )
__global__ __launch_bounds__(256) void gemm_h1_fused(
    const unsigned short* __restrict__ P,
    const unsigned short* __restrict__ feats_bf,
    const unsigned short* __restrict__ Bt,
    const float* __restrict__ b0, const float* __restrict__ bv,
    const float* __restrict__ norm,
    unsigned char* __restrict__ h1_fp8) {
  __shared__ unsigned short Bs[64][256];
  int mb, nh;
  gemm_tile(blockIdx.x, &mb, &nh);
  if (mb >= MBLOCKS) return;

  int tid = threadIdx.x;
  int lane = tid & 63;
  int wv = tid >> 6;
  int ln15 = lane & 15;
  int g = lane >> 4;

  int m0 = mb * 128 + wv * 32;
  int r0 = m0 + ln15;
  int r1 = m0 + 16 + ln15;
  if (r0 >= N_NODES) r0 = N_NODES - 1;
  if (r1 >= N_NODES) r1 = N_NODES - 1;

  bf16x8 a0[8], a1[8];  // s=0..3 from P (k<128), s=4..7 from feats (k>=128)
#pragma unroll
  for (int s = 0; s < 4; ++s) {
    a0[s] = *(const bf16x8*)(P + (size_t)r0 * 128 + g * 8 + s * 32);
    a1[s] = *(const bf16x8*)(P + (size_t)r1 * 128 + g * 8 + s * 32);
    a0[s + 4] = *(const bf16x8*)(feats_bf + (size_t)r0 * 128 + g * 8 + s * 32);
    a1[s + 4] = *(const bf16x8*)(feats_bf + (size_t)r1 * 128 + g * 8 + s * 32);
  }

  float nA[4], nB[4];
#pragma unroll
  for (int r = 0; r < 4; ++r) {
    int mA = m0 + g * 4 + r;
    int mB = m0 + 16 + g * 4 + r;
    nA[r] = (mA < N_NODES) ? norm[mA] : 0.f;
    nB[r] = (mB < N_NODES) ? norm[mB] : 0.f;
  }

  for (int stk = 0; stk < 3; ++stk) {
    if (stk) __syncthreads();
    stage_B64(Bs, Bt + (size_t)stk * 32768, nh, tid);
    __syncthreads();

    f32x4 acc0[4], acc1[4];
#pragma unroll
    for (int nt = 0; nt < 4; ++nt) { acc0[nt] = (f32x4)(0.f); acc1[nt] = (f32x4)(0.f); }

#pragma unroll
    for (int s = 0; s < 8; ++s) {
#pragma unroll
      for (int nt = 0; nt < 4; ++nt) {
        bf16x8 bfr = read_B64(Bs, nt * 16 + ln15, s * 4 + g);
        acc0[nt] = __builtin_amdgcn_mfma_f32_16x16x32_bf16(a0[s], bfr, acc0[nt], 0, 0, 0);
        acc1[nt] = __builtin_amdgcn_mfma_f32_16x16x32_bf16(a1[s], bfr, acc1[nt], 0, 0, 0);
      }
    }

#pragma unroll
    for (int nt = 0; nt < 4; ++nt) {
      int colj = nh + nt * 16 + ln15;
      float bsum = b0[stk * 128 + colj] + bv[stk * 128 + colj];
#pragma unroll
      for (int r = 0; r < 4; ++r) {
        int mA = m0 + g * 4 + r;
        int mB = m0 + 16 + g * 4 + r;
        if (mA < N_NODES) {
          float x = acc0[nt][r] + bsum;
          x = x > 0.f ? x : 0.f;
          h1_fp8[(size_t)mA * 384 + stk * 128 + colj] = f32_to_fp8(x * nA[r]);
        }
        if (mB < N_NODES) {
          float x = acc1[nt][r] + bsum;
          x = x > 0.f ? x : 0.f;
          h1_fp8[(size_t)mB * 384 + stk * 128 + colj] = f32_to_fp8(x * nB[r]);
        }
      }
    }
  }
}

// layer-2 fused: out = (1/3) * sum_stk relu(agg[stk] @ w[stk] + feats @ v[stk] + bw + bv)
__global__ __launch_bounds__(256) void gemm_out_fused(
    const unsigned short* __restrict__ agg,
    const unsigned short* __restrict__ feats_bf,
    const unsigned short* __restrict__ Bt,
    const float* __restrict__ bwp, const float* __restrict__ bvp,
    float* __restrict__ outp) {
  __shared__ unsigned short Bs[64][256];
  int mb, nh;
  gemm_tile(blockIdx.x, &mb, &nh);
  if (mb >= MBLOCKS) return;

  int tid = threadIdx.x;
  int lane = tid & 63;
  int wv = tid >> 6;
  int ln15 = lane & 15;
  int g = lane >> 4;

  int m0 = mb * 128 + wv * 32;
  int r0 = m0 + ln15;
  int r1 = m0 + 16 + ln15;
  if (r0 >= N_NODES) r0 = N_NODES - 1;
  if (r1 >= N_NODES) r1 = N_NODES - 1;

  bf16x8 f0[4], f1[4];  // feats frags (k=128..255 phase)
#pragma unroll
  for (int s = 0; s < 4; ++s) {
    f0[s] = *(const bf16x8*)(feats_bf + (size_t)r0 * 128 + g * 8 + s * 32);
    f1[s] = *(const bf16x8*)(feats_bf + (size_t)r1 * 128 + g * 8 + s * 32);
  }

  f32x4 sum0[4], sum1[4];
#pragma unroll
  for (int nt = 0; nt < 4; ++nt) { sum0[nt] = (f32x4)(0.f); sum1[nt] = (f32x4)(0.f); }

  for (int stk = 0; stk < 3; ++stk) {
    if (stk) __syncthreads();
    stage_B64(Bs, Bt + (size_t)stk * 32768, nh, tid);
    __syncthreads();

    const unsigned short* A1 = agg + (size_t)stk * PLANE;
    bf16x8 g0[4], g1[4];
#pragma unroll
    for (int s = 0; s < 4; ++s) {
      g0[s] = *(const bf16x8*)(A1 + (size_t)r0 * 128 + g * 8 + s * 32);
      g1[s] = *(const bf16x8*)(A1 + (size_t)r1 * 128 + g * 8 + s * 32);
    }

    f32x4 acc0[4], acc1[4];
#pragma unroll
    for (int nt = 0; nt < 4; ++nt) { acc0[nt] = (f32x4)(0.f); acc1[nt] = (f32x4)(0.f); }

#pragma unroll
    for (int s = 0; s < 8; ++s) {
      bf16x8 af0 = (s < 4) ? g0[s & 3] : f0[s & 3];
      bf16x8 af1 = (s < 4) ? g1[s & 3] : f1[s & 3];
#pragma unroll
      for (int nt = 0; nt < 4; ++nt) {
        bf16x8 bfr = read_B64(Bs, nt * 16 + ln15, s * 4 + g);
        acc0[nt] = __builtin_amdgcn_mfma_f32_16x16x32_bf16(af0, bfr, acc0[nt], 0, 0, 0);
        acc1[nt] = __builtin_amdgcn_mfma_f32_16x16x32_bf16(af1, bfr, acc1[nt], 0, 0, 0);
      }
    }

#pragma unroll
    for (int nt = 0; nt < 4; ++nt) {
      int colj = nh + nt * 16 + ln15;
      float bsum = bwp[stk * 128 + colj] + bvp[stk * 128 + colj];
#pragma unroll
      for (int r = 0; r < 4; ++r) {
        float x0 = acc0[nt][r] + bsum;
        float x1 = acc1[nt][r] + bsum;
        sum0[nt][r] += (x0 > 0.f ? x0 : 0.f);
        sum1[nt][r] += (x1 > 0.f ? x1 : 0.f);
      }
    }
  }

  const float sc = 1.0f / 3.0f;
#pragma unroll
  for (int nt = 0; nt < 4; ++nt) {
    int colj = nh + nt * 16 + ln15;
#pragma unroll
    for (int r = 0; r < 4; ++r) {
      int mA = m0 + g * 4 + r;
      int mB = m0 + 16 + g * 4 + r;
      if (mA < N_NODES) outp[(size_t)mA * 128 + colj] = sum0[nt][r] * sc;
      if (mB < N_NODES) outp[(size_t)mB * 128 + colj] = sum1[nt][r] * sc;
    }
  }
}

// ---------------- launcher ----------------

extern "C" void kernel_launch(void* const* d_in, const int* in_sizes, int n_in,
                              void* d_out, int out_size, void* d_ws, size_t ws_size,
                              hipStream_t stream) {
  const float* feats = (const float*)d_in[0];
  const int* src = (const int*)d_in[1];
  const int* dst = (const int*)d_in[2];
  const float* w0 = (const float*)d_in[3];
  const float* b0 = (const float*)d_in[4];
  const float* w = (const float*)d_in[5];
  const float* bw = (const float*)d_in[6];
  const float* v = (const float*)d_in[7];
  const float* bv = (const float*)d_in[8];
  float* out = (float*)d_out;

  char* ws = (char*)d_ws;
  size_t off = 0;
  auto alloc = [&](size_t bytes) {
    void* p = ws + off;
    off += (bytes + 255) & ~(size_t)255;
    return p;
  };
  // packed counters + bucket counters contiguous so one memset clears all
  unsigned* cnt2p = (unsigned*)alloc((NW2 + 128) * 4);
  int* bcnt = (int*)cnt2p + NW2;
  int* gcur = bcnt + 64;
  int* local2 = (int*)alloc(NB2 * 4);
  int* partial = (int*)alloc(NCHUNK2 * 4);
  int* chunk_off = (int*)alloc(NCHUNK2 * 4);
  float* norm = (float*)alloc(N_NODES * 4);
  int* rowptr2 = (int*)alloc((NB2 + 1) * 4);
  int* col = (int*)alloc(N_EDGES * 4);
  int* perm = (int*)alloc(N_NODES * 4);
  int* rank_pack = (int*)alloc(N_EDGES * 4);
  unsigned short* bt_h1 = (unsigned short*)alloc(3 * 32768 * 2);
  unsigned short* bt_out = (unsigned short*)alloc(3 * 32768 * 2);

  size_t pb = PLANE * 2;  // bf16 plane bytes
  unsigned short* feats_bf = (unsigned short*)alloc(pb);
  unsigned char* feats_fp8 = (unsigned char*)alloc(PLANE);
  unsigned short* P_bf = (unsigned short*)alloc(pb);
  unsigned char* h1_fp8 = (unsigned char*)alloc(3 * PLANE);  // interleaved [node][3][128]
  unsigned short* agg_bf = (unsigned short*)alloc(3 * pb);

  hipMemsetAsync(cnt2p, 0, (NW2 + 128) * 4, stream);

  dim3 blk(256);
  // prep: edges-first (atomic latency overlapped by conv streaming behind it)
  prep_all<<<(PREP_TOTAL + 255) / 256, blk, 0, stream>>>(feats, w0, w, v, src, dst,
                                                         feats_bf, bt_h1, bt_out, cnt2p,
                                                         rank_pack);
  scan_local2<<<NCHUNK2 + NROWBLK, blk, 0, stream>>>(cnt2p, local2, partial, bcnt);
  scan_chunks2<<<1, blk, 0, stream>>>(partial, chunk_off, rowptr2 + NB2, bcnt, gcur);
  finalize2<<<NCHUNK2 + NROWBLK, blk, 0, stream>>>(local2, chunk_off, cnt2p, rowptr2,
                                                   norm, gcur, perm);
  // atomic-free band-sorted CSR fill (edges first) + feats_fp8 = fp8(norm * feats)
  csr_fp8<<<(CONV_THREADS + N_EDGES + 255) / 256, blk, 0, stream>>>(
      src, rank_pack, rowptr2, col, feats, norm, feats_fp8);

  int sblocks = (N_NODES + 31) / 32;  // 32 rows per block (8 lanes/row)

  // P = propagate(feats)   (src-norm pre-folded; dst-norm in epilogue)
  spmm_rows<1, 128><<<sblocks, blk, 0, stream>>>(feats_fp8, norm, rowptr2, col, perm, P_bf);
  // h1[node][k][:] = fp8(norm * relu(P @ w0[k] + feats @ v[k] + b0[k] + bv[k]))
  gemm_h1_fused<<<GEMM_GRID, blk, 0, stream>>>(P_bf, feats_bf, bt_h1, b0, bv, norm, h1_fp8);
  // agg[k] = propagate(h1[k])  (interleaved gather: 384 B/edge contiguous, band-sorted)
  spmm_rows<3, 384><<<sblocks, blk, 0, stream>>>(h1_fp8, norm, rowptr2, col, perm, agg_bf);
  // out = (1/3) * sum_k relu(agg[k] @ w[k] + feats @ v[k] + bw[k] + bv[k])
  gemm_out_fused<<<GEMM_GRID, blk, 0, stream>>>(agg_bf, feats_bf, bt_out, bw, bv, out);
}